// Round 11
// baseline (480.815 us; speedup 1.0000x reference)
//
#include <hip/hip_runtime.h>

#define B_ 4
#define NH_ 32
#define SQ_ 512
#define HD_ 128
#define MLEN_ 3584
#define KT_ 4096           // MLEN_ + SQ_
#define QB_ 64
#define KB_ 32
#define NTILE_ 128         // KT_ / KB_
#define MEMTILES_ 112      // MLEN_ / KB_

typedef float f32x4 __attribute__((ext_vector_type(4)));
typedef short s16x8 __attribute__((ext_vector_type(8)));

__device__ __forceinline__ f32x4 MFMA16(s16x8 a, s16x8 b, f32x4 c) {
    return __builtin_amdgcn_mfma_f32_16x16x32_bf16(a, b, c, 0, 0, 0);
}

__device__ __forceinline__ s16x8 cvt8(float4 a, float4 b) {
    union { s16x8 v; __bf16 h[8]; } u;
    u.h[0] = (__bf16)a.x; u.h[1] = (__bf16)a.y;
    u.h[2] = (__bf16)a.z; u.h[3] = (__bf16)a.w;
    u.h[4] = (__bf16)b.x; u.h[5] = (__bf16)b.y;
    u.h[6] = (__bf16)b.z; u.h[7] = (__bf16)b.w;
    return u.v;
}

// 4 waves x 16 q-rows (QB=64), KB=32, 16KB LDS -> 4 independent blocks/CU.
// R6's per-thread dataflow exactly (same bytes/thread, same instr mix);
// only the decomposition changes: 4 small barrier domains dephase so
// stage(A) overlaps compute(B,C,D). Proven-win mechanism (R4) pushed further.
__launch_bounds__(256, 4)
__global__ void attn_kernel(const float* __restrict__ q, const float* __restrict__ k,
                            const float* __restrict__ v, const float* __restrict__ mask,
                            const float* __restrict__ mem, float* __restrict__ ctx)
{
    __shared__ __bf16 Kb[KB_ * HD_];        // 8 KB, swizzled rows (256B rows)
    __shared__ __bf16 Vtb[HD_ * KB_];       // 8 KB, transposed + swizzled (64B rows)

    const int tid  = threadIdx.x;
    const int lane = tid & 63;
    const int w    = tid >> 6;              // 0..3
    const int l15  = lane & 15;
    const int l4   = lane >> 4;             // 0..3
    const int xv   = (lane & 7) << 4;       // K-row swizzle key (row&7 = l15&7)

    // grid = 1024: qt 0..7; same head's 8 q-tiles are bid%128-equal -> same XCD
    const int qt   = blockIdx.x >> 7;
    const int pair = blockIdx.x & 127;
    const int b    = pair >> 5;
    const int h    = pair & 31;
    const int q0   = qt * QB_;

    // ---- Q fragments (B-operand; lane l15 = q-row, k-elem = l4*8+j = d) ----
    const float scale = 0.088388347648318447f;   // 1/sqrt(128)
    s16x8 qf[4];
    {
        const float* qbase = q + (((size_t)(b * NH_ + h)) * SQ_ + q0 + w * 16 + l15) * HD_;
        #pragma unroll
        for (int kc = 0; kc < 4; ++kc) {
            const float* p = qbase + kc * 32 + l4 * 8;
            float4 a = *(const float4*)p;
            float4 c = *(const float4*)(p + 4);
            a.x *= scale; a.y *= scale; a.z *= scale; a.w *= scale;
            c.x *= scale; c.y *= scale; c.z *= scale; c.w *= scale;
            qf[kc] = cvt8(a, c);
        }
    }

    f32x4 acc[8];
    #pragma unroll
    for (int n = 0; n < 8; ++n) acc[n] = (f32x4){0.f, 0.f, 0.f, 0.f};

    float mrun = -3.0e38f, lrun = 0.f;      // per-lane stats for q = w*16 + l15

    const float* maskrow = mask + ((size_t)b * SQ_ + q0 + w * 16 + l15) * KT_;

    const int krow = tid >> 4,  kcg  = tid & 15;   // K unit: rows 0..15 (+16 on it 1)
    const int vhd  = tid & 127, vkvb = tid >> 7;   // V unit: kvb {0,1} (+2 on it 1)
    const int vswz = (vhd & 3) ^ ((vhd >> 2) & 3); // V^T row swizzle key

    for (int t = 0; t < NTILE_; ++t) {
        const int kv0 = t * KB_;
        const float *srcK, *srcV;
        int rstride;
        if (t < MEMTILES_) {
            const float* mrow = mem + ((size_t)b * MLEN_ + kv0) * (2 * NH_ * HD_) + h * HD_;
            srcK = mrow;
            srcV = mrow + NH_ * HD_;
            rstride = 2 * NH_ * HD_;
        } else {
            size_t off = (((size_t)b * NH_ + h) * SQ_ + (kv0 - MLEN_)) * HD_;
            srcK = k + off;
            srcV = v + off;
            rstride = HD_;
        }

        __syncthreads();   // previous tile's LDS reads complete

        // ---- K stage: 512 x 16B chunks over 256 threads (2 its) ----
        #pragma unroll
        for (int it = 0; it < 2; ++it) {
            int row = krow + it * 16;
            const float* p = srcK + (size_t)row * rstride + kcg * 8;
            float4 a = *(const float4*)p;
            float4 c = *(const float4*)(p + 4);
            int byte = row * 256 + ((kcg * 16) ^ ((row & 7) << 4));
            *(s16x8*)((char*)Kb + byte) = cvt8(a, c);
        }
        // ---- V stage (transposed): 64B rows, full-32-bank swizzle ----
        #pragma unroll
        for (int it = 0; it < 2; ++it) {
            int kvb = vkvb + it * 2;
            const float* p = srcV + (size_t)(kvb * 8) * rstride + vhd;
            union { s16x8 v; __bf16 hh[8]; } u;
            #pragma unroll
            for (int j = 0; j < 8; ++j) u.hh[j] = (__bf16)p[(size_t)j * rstride];
            int byte = vhd * 64 + (((kvb ^ vswz) & 3) << 4);
            *(s16x8*)((char*)Vtb + byte) = u.v;
        }

        // ---- mask loads (same barrier region as stage) ----
        f32x4 mk0 = *(const f32x4*)(maskrow + kv0 + l4 * 4);
        f32x4 mk1 = *(const f32x4*)(maskrow + kv0 + 16 + l4 * 4);

        __syncthreads();   // tile staged

        // ---- S^T = K @ Q^T : st[mt] rows kv = mt*16 + l4*4 + r, cols q = l15 ----
        f32x4 st[2];
        st[0] = (f32x4){0.f, 0.f, 0.f, 0.f};
        st[1] = (f32x4){0.f, 0.f, 0.f, 0.f};
        __builtin_amdgcn_s_setprio(1);
        #pragma unroll
        for (int mt = 0; mt < 2; ++mt) {
            #pragma unroll
            for (int kc = 0; kc < 4; ++kc) {
                s16x8 kf = *(const s16x8*)((const char*)Kb +
                            (mt * 16 + l15) * 256 + (((kc * 4 + l4) * 16) ^ xv));
                st[mt] = MFMA16(kf, qf[kc], st[mt]);
            }
        }
        __builtin_amdgcn_s_setprio(0);

        // ---- mask apply ----
        #pragma unroll
        for (int r = 0; r < 4; ++r) {
            st[0][r] = fmaf(mk0[r], st[0][r] + 10000.f, -10000.f);
            st[1][r] = fmaf(mk1[r], st[1][r] + 10000.f, -10000.f);
        }

        // ---- in-register softmax over kv (8 vals + 2 shfl) ----
        float rm = fmaxf(fmaxf(fmaxf(st[0][0], st[0][1]), fmaxf(st[0][2], st[0][3])),
                         fmaxf(fmaxf(st[1][0], st[1][1]), fmaxf(st[1][2], st[1][3])));
        rm = fmaxf(rm, __shfl_xor(rm, 16));
        rm = fmaxf(rm, __shfl_xor(rm, 32));

        if (!__all(rm <= mrun + 8.f)) {     // defer-max
            float nm = fmaxf(mrun, rm);
            float al = __expf(mrun - nm);
            mrun = nm;
            lrun *= al;
            float alr0 = __shfl(al, l4 * 4 + 0);
            float alr1 = __shfl(al, l4 * 4 + 1);
            float alr2 = __shfl(al, l4 * 4 + 2);
            float alr3 = __shfl(al, l4 * 4 + 3);
            #pragma unroll
            for (int nn = 0; nn < 8; ++nn) {
                acc[nn][0] *= alr0; acc[nn][1] *= alr1;
                acc[nn][2] *= alr2; acc[nn][3] *= alr3;
            }
        }

        float rs = 0.f;
        #pragma unroll
        for (int mt = 0; mt < 2; ++mt)
            #pragma unroll
            for (int r = 0; r < 4; ++r) {
                float pe = __expf(st[mt][r] - mrun);
                st[mt][r] = pe;
                rs += pe;
            }
        rs += __shfl_xor(rs, 16);
        rs += __shfl_xor(rs, 32);
        lrun += rs;

        // ---- pack P^T to bf16 ----
        union PK { int d[2]; __bf16 hh[4]; };
        PK pk0, pk1;
        pk0.hh[0]=(__bf16)st[0][0]; pk0.hh[1]=(__bf16)st[0][1];
        pk0.hh[2]=(__bf16)st[0][2]; pk0.hh[3]=(__bf16)st[0][3];
        pk1.hh[0]=(__bf16)st[1][0]; pk1.hh[1]=(__bf16)st[1][1];
        pk1.hh[2]=(__bf16)st[1][2]; pk1.hh[3]=(__bf16)st[1][3];

        // ---- assemble PV A-fragment: lane needs P[q=l15][kv=l4*8+j] ----
        const int srcA = (l4 & 1) * 32 + l15;
        const int srcB = srcA + 16;
        const int sel  = l4 >> 1;            // which mt
        s16x8 pa;
        {
            union { int d[4]; s16x8 v; } ua;
            int a0 = __shfl(pk0.d[0], srcA), a1 = __shfl(pk0.d[1], srcA);
            int b0 = __shfl(pk1.d[0], srcA), b1 = __shfl(pk1.d[1], srcA);
            int a2 = __shfl(pk0.d[0], srcB), a3 = __shfl(pk0.d[1], srcB);
            int b2 = __shfl(pk1.d[0], srcB), b3 = __shfl(pk1.d[1], srcB);
            ua.d[0] = sel ? b0 : a0; ua.d[1] = sel ? b1 : a1;
            ua.d[2] = sel ? b2 : a2; ua.d[3] = sel ? b3 : a3;
            pa = ua.v;
        }

        // ---- O += P @ V ----
        __builtin_amdgcn_s_setprio(1);
        #pragma unroll
        for (int nn = 0; nn < 8; ++nn) {
            int hdv = nn * 16 + l15;
            int hswz = (hdv & 3) ^ ((hdv >> 2) & 3);
            s16x8 vf = *(const s16x8*)((const char*)Vtb +
                         hdv * 64 + (((l4 ^ hswz) & 3) << 4));
            acc[nn] = MFMA16(pa, vf, acc[nn]);
        }
        __builtin_amdgcn_s_setprio(0);
    }

    // ---- epilogue ----
    float lr0 = __shfl(lrun, l4 * 4 + 0);
    float lr1 = __shfl(lrun, l4 * 4 + 1);
    float lr2 = __shfl(lrun, l4 * 4 + 2);
    float lr3 = __shfl(lrun, l4 * 4 + 3);
    float inv0 = 1.f / lr0, inv1 = 1.f / lr1, inv2 = 1.f / lr2, inv3 = 1.f / lr3;
    float* obase = ctx + (((size_t)(b * NH_ + h)) * SQ_ + q0 + w * 16 + l4 * 4) * HD_ + l15;
    #pragma unroll
    for (int nn = 0; nn < 8; ++nn) {
        obase[(size_t)0 * HD_ + nn * 16] = acc[nn][0] * inv0;
        obase[(size_t)1 * HD_ + nn * 16] = acc[nn][1] * inv1;
        obase[(size_t)2 * HD_ + nn * 16] = acc[nn][2] * inv2;
        obase[(size_t)3 * HD_ + nn * 16] = acc[nn][3] * inv3;
    }
}

// cache_kv: out[b][s][part][h][d] = (part ? v : k)[b][h][s][d]
__global__ void cachekv_kernel(const float* __restrict__ k, const float* __restrict__ v,
                               float* __restrict__ out)
{
    size_t i = ((size_t)blockIdx.x * 256 + threadIdx.x) * 4;
    unsigned f = (unsigned)i;
    unsigned d    = f & 127;
    unsigned hh   = (f >> 7) & 31;
    unsigned part = (f >> 12) & 1;
    unsigned s    = (f >> 13) & 511;
    unsigned bb   = f >> 22;
    const float* src = (part ? v : k) + (((size_t)(bb * 32u + hh)) * 512u + s) * 128u + d;
    *(float4*)(out + i) = *(const float4*)src;
}

extern "C" void kernel_launch(void* const* d_in, const int* in_sizes, int n_in,
                              void* d_out, int out_size, void* d_ws, size_t ws_size,
                              hipStream_t stream) {
    const float* q    = (const float*)d_in[0];
    const float* k    = (const float*)d_in[1];
    const float* v    = (const float*)d_in[2];
    const float* mask = (const float*)d_in[3];
    const float* mem  = (const float*)d_in[4];
    float* out = (float*)d_out;

    attn_kernel<<<dim3(B_ * NH_ * (SQ_ / QB_)), dim3(256), 0, stream>>>(q, k, v, mask, mem, out);

    const int ctx_elems = B_ * NH_ * SQ_ * HD_;                 // 8388608
    const int ckv_elems = B_ * SQ_ * 2 * NH_ * HD_;             // 16777216
    cachekv_kernel<<<dim3(ckv_elems / 4 / 256), dim3(256), 0, stream>>>(k, v, out + ctx_elems);
    (void)in_sizes; (void)n_in; (void)out_size; (void)d_ws; (void)ws_size;
}

// Round 12
// 329.033 us; speedup vs baseline: 1.4613x; 1.4613x over previous
//
#include <hip/hip_runtime.h>

#define B_ 4
#define NH_ 32
#define SQ_ 512
#define HD_ 128
#define MLEN_ 3584
#define KT_ 4096           // MLEN_ + SQ_
#define QB_ 128
#define KB_ 32
#define NTILE_ 128         // KT_ / KB_
#define MEMTILES_ 112      // MLEN_ / KB_

typedef float f32x4 __attribute__((ext_vector_type(4)));
typedef short s16x8 __attribute__((ext_vector_type(8)));

__device__ __forceinline__ f32x4 MFMA16(s16x8 a, s16x8 b, f32x4 c) {
    return __builtin_amdgcn_mfma_f32_16x16x32_bf16(a, b, c, 0, 0, 0);
}

__device__ __forceinline__ s16x8 cvt8(float4 a, float4 b) {
    union { s16x8 v; __bf16 h[8]; } u;
    u.h[0] = (__bf16)a.x; u.h[1] = (__bf16)a.y;
    u.h[2] = (__bf16)a.z; u.h[3] = (__bf16)a.w;
    u.h[4] = (__bf16)b.x; u.h[5] = (__bf16)b.y;
    u.h[6] = (__bf16)b.z; u.h[7] = (__bf16)b.w;
    return u.v;
}

// 4 waves x 32 q-rows (QB=128 preserved -> KV sharing intact), KB=32.
// Halves per-CU LDS traffic vs R6 (4 waves re-read each K/V tile, not 8;
// each PV vf read feeds 2 MFMAs). launch_bounds(256,2) -> 2 waves/SIMD ->
// 256-VGPR budget: register double-buffer prefetch fits WITHOUT spill
// (R7-R9 failed at the 128-VGPR/4-wave budget). LDS dbuf 32KB, 1 barrier/tile.
__launch_bounds__(256, 2)
__global__ void attn_kernel(const float* __restrict__ q, const float* __restrict__ k,
                            const float* __restrict__ v, const float* __restrict__ mask,
                            const float* __restrict__ mem, float* __restrict__ ctx)
{
    __shared__ __bf16 Kb[2][KB_ * HD_];     // 2 x 8 KB, swizzled rows (256B rows)
    __shared__ __bf16 Vtb[2][HD_ * KB_];    // 2 x 8 KB, transposed (64B rows)

    const int tid  = threadIdx.x;
    const int lane = tid & 63;
    const int w    = tid >> 6;              // 0..3
    const int l15  = lane & 15;
    const int l4   = lane >> 4;             // 0..3
    const int xv   = (lane & 7) << 4;       // K-row swizzle key

    // grid = 512: qt 0..3; same head's q-tiles are bid%128-equal -> same XCD
    const int qt   = blockIdx.x >> 7;
    const int pair = blockIdx.x & 127;
    const int b    = pair >> 5;
    const int h    = pair & 31;
    const int q0   = qt * QB_;

    // ---- Q fragments, m = 0,1 row-subtiles; wave rows q0 + w*32 + m*16 + l15 ----
    const float scale = 0.088388347648318447f;   // 1/sqrt(128)
    s16x8 qf[2][4];
    {
        const float* qbase = q + (((size_t)(b * NH_ + h)) * SQ_ + q0 + w * 32 + l15) * HD_;
        #pragma unroll
        for (int m = 0; m < 2; ++m)
            #pragma unroll
            for (int kc = 0; kc < 4; ++kc) {
                const float* p = qbase + (size_t)m * 16 * HD_ + kc * 32 + l4 * 8;
                float4 a = *(const float4*)p;
                float4 c = *(const float4*)(p + 4);
                a.x *= scale; a.y *= scale; a.z *= scale; a.w *= scale;
                c.x *= scale; c.y *= scale; c.z *= scale; c.w *= scale;
                qf[m][kc] = cvt8(a, c);
            }
    }

    f32x4 acc[2][8];
    #pragma unroll
    for (int m = 0; m < 2; ++m)
        #pragma unroll
        for (int n = 0; n < 8; ++n) acc[m][n] = (f32x4){0.f, 0.f, 0.f, 0.f};

    float mrun[2] = {-3.0e38f, -3.0e38f}, lrun[2] = {0.f, 0.f};

    const float* maskrow = mask + ((size_t)b * SQ_ + q0 + w * 32 + l15) * KT_;

    const int krow = tid >> 4,  kcg  = tid & 15;   // K unit: rows 0..15 (+16 it1)
    const int vhd  = tid & 127, vkvb = tid >> 7;   // V unit: kvb {0,1} (+2 it1)
    const int vsw  = (vhd >> 1) & 3;               // V^T write-slot key (conflict-free)

    // ---- prologue: stage tile 0 into buf 0 ----
    {
        const float* mrow = mem + ((size_t)b * MLEN_) * (2 * NH_ * HD_) + h * HD_;
        const float* srcK = mrow;
        const float* srcV = mrow + NH_ * HD_;
        const int rs = 2 * NH_ * HD_;
        #pragma unroll
        for (int it = 0; it < 2; ++it) {
            int row = krow + it * 16;
            const float* p = srcK + (size_t)row * rs + kcg * 8;
            float4 a = *(const float4*)p;
            float4 c = *(const float4*)(p + 4);
            int byte = row * 256 + ((kcg * 16) ^ ((row & 7) << 4));
            *(s16x8*)((char*)Kb[0] + byte) = cvt8(a, c);
        }
        #pragma unroll
        for (int it = 0; it < 2; ++it) {
            int kvb = vkvb + it * 2;
            const float* p = srcV + (size_t)(kvb * 8) * rs + vhd;
            union { s16x8 v; __bf16 hh[8]; } u;
            #pragma unroll
            for (int j = 0; j < 8; ++j) u.hh[j] = (__bf16)p[(size_t)j * rs];
            int byte = vhd * 64 + (((kvb ^ vsw) & 3) << 4);
            *(s16x8*)((char*)Vtb[0] + byte) = u.v;
        }
    }
    __syncthreads();

    for (int t = 0; t < NTILE_; ++t) {
        const int cur = t & 1;
        const int kv0 = t * KB_;
        const bool havenext = (t + 1 < NTILE_);

        // ---- mask loads for tile t FIRST (retire before KV(t+1), in-order) ----
        f32x4 mk[2][2];
        #pragma unroll
        for (int m = 0; m < 2; ++m)
            #pragma unroll
            for (int mt = 0; mt < 2; ++mt)
                mk[m][mt] = *(const f32x4*)(maskrow + (size_t)m * 16 * KT_ +
                                            kv0 + mt * 16 + l4 * 4);

        // ---- KV(t+1) loads (consumed only by stage-writes after compute) ----
        float4 ka0, kb0, ka1, kb1;
        float vp0[8], vp1[8];
        if (havenext) {
            const float *srcK, *srcV; int rs;
            const int nkv0 = (t + 1) * KB_;
            if (t + 1 < MEMTILES_) {
                const float* mrow = mem + ((size_t)b * MLEN_ + nkv0) * (2 * NH_ * HD_) + h * HD_;
                srcK = mrow; srcV = mrow + NH_ * HD_; rs = 2 * NH_ * HD_;
            } else {
                size_t off = (((size_t)b * NH_ + h) * SQ_ + (nkv0 - MLEN_)) * HD_;
                srcK = k + off; srcV = v + off; rs = HD_;
            }
            const float* p0 = srcK + (size_t)krow * rs + kcg * 8;
            ka0 = *(const float4*)p0; kb0 = *(const float4*)(p0 + 4);
            const float* p1 = srcK + (size_t)(krow + 16) * rs + kcg * 8;
            ka1 = *(const float4*)p1; kb1 = *(const float4*)(p1 + 4);
            const float* q0p = srcV + (size_t)(vkvb * 8) * rs + vhd;
            #pragma unroll
            for (int j = 0; j < 8; ++j) vp0[j] = q0p[(size_t)j * rs];
            const float* q1p = srcV + (size_t)((vkvb + 2) * 8) * rs + vhd;
            #pragma unroll
            for (int j = 0; j < 8; ++j) vp1[j] = q1p[(size_t)j * rs];
        }

        // ---- S^T = K @ Q^T : st[m][mt] rows kv = mt*16+l4*4+r, cols q-sub = l15 ----
        f32x4 st[2][2];
        st[0][0] = (f32x4){0.f,0.f,0.f,0.f}; st[0][1] = (f32x4){0.f,0.f,0.f,0.f};
        st[1][0] = (f32x4){0.f,0.f,0.f,0.f}; st[1][1] = (f32x4){0.f,0.f,0.f,0.f};
        __builtin_amdgcn_s_setprio(1);
        #pragma unroll
        for (int mt = 0; mt < 2; ++mt) {
            #pragma unroll
            for (int kc = 0; kc < 4; ++kc) {
                s16x8 kf = *(const s16x8*)((const char*)Kb[cur] +
                            (mt * 16 + l15) * 256 + (((kc * 4 + l4) * 16) ^ xv));
                st[0][mt] = MFMA16(kf, qf[0][kc], st[0][mt]);
                st[1][mt] = MFMA16(kf, qf[1][kc], st[1][mt]);
            }
        }
        __builtin_amdgcn_s_setprio(0);

        // ---- mask + softmax + pack, per m ----
        s16x8 pa[2];
        #pragma unroll
        for (int m = 0; m < 2; ++m) {
            #pragma unroll
            for (int mt = 0; mt < 2; ++mt)
                #pragma unroll
                for (int r = 0; r < 4; ++r)
                    st[m][mt][r] = fmaf(mk[m][mt][r], st[m][mt][r] + 10000.f, -10000.f);

            float rm = fmaxf(fmaxf(fmaxf(st[m][0][0], st[m][0][1]),
                                   fmaxf(st[m][0][2], st[m][0][3])),
                             fmaxf(fmaxf(st[m][1][0], st[m][1][1]),
                                   fmaxf(st[m][1][2], st[m][1][3])));
            rm = fmaxf(rm, __shfl_xor(rm, 16));
            rm = fmaxf(rm, __shfl_xor(rm, 32));

            if (!__all(rm <= mrun[m] + 8.f)) {    // defer-max
                float nm = fmaxf(mrun[m], rm);
                float al = __expf(mrun[m] - nm);
                mrun[m] = nm;
                lrun[m] *= al;
                float a0 = __shfl(al, l4 * 4 + 0);
                float a1 = __shfl(al, l4 * 4 + 1);
                float a2 = __shfl(al, l4 * 4 + 2);
                float a3 = __shfl(al, l4 * 4 + 3);
                #pragma unroll
                for (int nn = 0; nn < 8; ++nn) {
                    acc[m][nn][0] *= a0; acc[m][nn][1] *= a1;
                    acc[m][nn][2] *= a2; acc[m][nn][3] *= a3;
                }
            }

            float rs = 0.f;
            #pragma unroll
            for (int mt = 0; mt < 2; ++mt)
                #pragma unroll
                for (int r = 0; r < 4; ++r) {
                    float pe = __expf(st[m][mt][r] - mrun[m]);
                    st[m][mt][r] = pe;
                    rs += pe;
                }
            rs += __shfl_xor(rs, 16);
            rs += __shfl_xor(rs, 32);
            lrun[m] += rs;

            union PK { int d[2]; __bf16 hh[4]; };
            PK pk0, pk1;
            pk0.hh[0]=(__bf16)st[m][0][0]; pk0.hh[1]=(__bf16)st[m][0][1];
            pk0.hh[2]=(__bf16)st[m][0][2]; pk0.hh[3]=(__bf16)st[m][0][3];
            pk1.hh[0]=(__bf16)st[m][1][0]; pk1.hh[1]=(__bf16)st[m][1][1];
            pk1.hh[2]=(__bf16)st[m][1][2]; pk1.hh[3]=(__bf16)st[m][1][3];

            const int srcA = (l4 & 1) * 32 + l15;
            const int srcB = srcA + 16;
            const int sel  = l4 >> 1;
            union { int d[4]; s16x8 v; } ua;
            int a0 = __shfl(pk0.d[0], srcA), a1 = __shfl(pk0.d[1], srcA);
            int b0 = __shfl(pk1.d[0], srcA), b1 = __shfl(pk1.d[1], srcA);
            int a2 = __shfl(pk0.d[0], srcB), a3 = __shfl(pk0.d[1], srcB);
            int b2 = __shfl(pk1.d[0], srcB), b3 = __shfl(pk1.d[1], srcB);
            ua.d[0] = sel ? b0 : a0; ua.d[1] = sel ? b1 : a1;
            ua.d[2] = sel ? b2 : a2; ua.d[3] = sel ? b3 : a3;
            pa[m] = ua.v;
        }

        // ---- O += P @ V : each vf read feeds BOTH m MFMAs ----
        __builtin_amdgcn_s_setprio(1);
        #pragma unroll
        for (int nn = 0; nn < 8; ++nn) {
            int hdv = nn * 16 + l15;
            s16x8 vf = *(const s16x8*)((const char*)Vtb[cur] +
                         hdv * 64 + (((l4 ^ ((hdv >> 1) & 3)) & 3) << 4));
            acc[0][nn] = MFMA16(pa[0], vf, acc[0][nn]);
            acc[1][nn] = MFMA16(pa[1], vf, acc[1][nn]);
        }
        __builtin_amdgcn_s_setprio(0);

        // ---- stage WRITES for t+1 into buf cur^1 (vmcnt waits land here) ----
        if (havenext) {
            int row0 = krow;
            int by0 = row0 * 256 + ((kcg * 16) ^ ((row0 & 7) << 4));
            *(s16x8*)((char*)Kb[cur ^ 1] + by0) = cvt8(ka0, kb0);
            int row1 = krow + 16;
            int by1 = row1 * 256 + ((kcg * 16) ^ ((row1 & 7) << 4));
            *(s16x8*)((char*)Kb[cur ^ 1] + by1) = cvt8(ka1, kb1);

            union { s16x8 v; __bf16 hh[8]; } u0, u1;
            #pragma unroll
            for (int j = 0; j < 8; ++j) u0.hh[j] = (__bf16)vp0[j];
            int vb0 = vhd * 64 + (((vkvb ^ vsw) & 3) << 4);
            *(s16x8*)((char*)Vtb[cur ^ 1] + vb0) = u0.v;
            #pragma unroll
            for (int j = 0; j < 8; ++j) u1.hh[j] = (__bf16)vp1[j];
            int vb1 = vhd * 64 + ((((vkvb + 2) ^ vsw) & 3) << 4);
            *(s16x8*)((char*)Vtb[cur ^ 1] + vb1) = u1.v;
        }

        __syncthreads();    // one barrier per tile
    }

    // ---- epilogue ----
    #pragma unroll
    for (int m = 0; m < 2; ++m) {
        float lr0 = __shfl(lrun[m], l4 * 4 + 0);
        float lr1 = __shfl(lrun[m], l4 * 4 + 1);
        float lr2 = __shfl(lrun[m], l4 * 4 + 2);
        float lr3 = __shfl(lrun[m], l4 * 4 + 3);
        float i0 = 1.f / lr0, i1 = 1.f / lr1, i2 = 1.f / lr2, i3 = 1.f / lr3;
        float* obase = ctx + (((size_t)(b * NH_ + h)) * SQ_ +
                              q0 + w * 32 + m * 16 + l4 * 4) * HD_ + l15;
        #pragma unroll
        for (int nn = 0; nn < 8; ++nn) {
            obase[(size_t)0 * HD_ + nn * 16] = acc[m][nn][0] * i0;
            obase[(size_t)1 * HD_ + nn * 16] = acc[m][nn][1] * i1;
            obase[(size_t)2 * HD_ + nn * 16] = acc[m][nn][2] * i2;
            obase[(size_t)3 * HD_ + nn * 16] = acc[m][nn][3] * i3;
        }
    }
}

// cache_kv: out[b][s][part][h][d] = (part ? v : k)[b][h][s][d]
__global__ void cachekv_kernel(const float* __restrict__ k, const float* __restrict__ v,
                               float* __restrict__ out)
{
    size_t i = ((size_t)blockIdx.x * 256 + threadIdx.x) * 4;
    unsigned f = (unsigned)i;
    unsigned d    = f & 127;
    unsigned hh   = (f >> 7) & 31;
    unsigned part = (f >> 12) & 1;
    unsigned s    = (f >> 13) & 511;
    unsigned bb   = f >> 22;
    const float* src = (part ? v : k) + (((size_t)(bb * 32u + hh)) * 512u + s) * 128u + d;
    *(float4*)(out + i) = *(const float4*)src;
}

extern "C" void kernel_launch(void* const* d_in, const int* in_sizes, int n_in,
                              void* d_out, int out_size, void* d_ws, size_t ws_size,
                              hipStream_t stream) {
    const float* q    = (const float*)d_in[0];
    const float* k    = (const float*)d_in[1];
    const float* v    = (const float*)d_in[2];
    const float* mask = (const float*)d_in[3];
    const float* mem  = (const float*)d_in[4];
    float* out = (float*)d_out;

    attn_kernel<<<dim3(B_ * NH_ * (SQ_ / QB_)), dim3(256), 0, stream>>>(q, k, v, mask, mem, out);

    const int ctx_elems = B_ * NH_ * SQ_ * HD_;                 // 8388608
    const int ckv_elems = B_ * SQ_ * 2 * NH_ * HD_;             // 16777216
    cachekv_kernel<<<dim3(ckv_elems / 4 / 256), dim3(256), 0, stream>>>(k, v, out + ctx_elems);
    (void)in_sizes; (void)n_in; (void)out_size; (void)d_ws; (void)ws_size;
}